// Round 11
// baseline (139.222 us; speedup 1.0000x reference)
//
#include <hip/hip_runtime.h>

#define T_DIM 512
#define B_DIM 128
#define E_DIM 256
#define NEG_INF (-1e30f)
#define W 16         // ids (consecutive t) per wave (R11: 8 -> 16, more sharing)
#define DONE 1e30f

typedef float vfloat4 __attribute__((ext_vector_type(4)));  // native vec for nt-store

// Closed-form stack math (exact max-plus identity):
//   rc_t[tau] = S[t] + max_{m in [tau,t]} g[m],  S = incl. prefix sum of (d-u),
//   g[m] = d[m] - S[m].
//   W[t][tau] != 0 only at right-to-left records of g (NGL chain from t),
//   truncated once S[t] + g[m] >= 1.
// R10 insight: write path exonerated (plain stores slightly worse; nt kept).
// Only sharing ever paid (R9). Final lever: W=16 per wave -> below-window
// shared-chain trips/id halve; hierarchy rows/id ~1.7 -> ~1.35.

struct Node { float g; int ngl; };   // g value + next-greater-to-left index

// Kernel 1: per-b prep. Shuffle wave-scan for S; sparse-table (range-max
// binary descend) for NGL: fixed 10 LDS probes per thread, no divergent scans.
__global__ void __launch_bounds__(512) scan_prep(
    const float* __restrict__ u, const float* __restrict__ d,
    float* __restrict__ S_out, Node* __restrict__ nodes)
{
    const int b    = blockIdx.x;
    const int t    = threadIdx.x;
    const int lane = t & 63;
    const int w    = t >> 6;          // 8 waves

    __shared__ float wsum[8];
    __shared__ float wpre[8];
    __shared__ float M[10][T_DIM];    // M[k][i] = max g over [max(0,i-2^k+1), i]

    const float dv = d[t * B_DIM + b];
    float x = dv - u[t * B_DIM + b];

    // wave-level inclusive scan (6 shfl steps)
    #pragma unroll
    for (int off = 1; off < 64; off <<= 1) {
        float y = __shfl_up(x, off, 64);
        if (lane >= off) x += y;
    }
    if (lane == 63) wsum[w] = x;
    __syncthreads();
    if (t < 8) {                       // tiny exclusive scan of 8 wave totals
        float s = 0.f;
        for (int i = 0; i < t; ++i) s += wsum[i];
        wpre[t] = s;
    }
    __syncthreads();
    const float S = x + wpre[w];       // inclusive prefix sum of (d-u)
    const float g = dv - S;

    // build sparse table: 9 levels of doubling window max
    M[0][t] = g;
    __syncthreads();
    #pragma unroll
    for (int k = 1; k < 10; ++k) {
        int h = 1 << (k - 1);
        float left = (t >= h) ? M[k - 1][t - h] : NEG_INF;
        float mk = fmaxf(M[k - 1][t], left);
        __syncthreads();               // level k-1 reads done
        M[k][t] = mk;
        __syncthreads();
    }

    // binary descend: largest m < t with g[m] > g (strict); else -1.
    int m = t - 1;
    #pragma unroll
    for (int k = 9; k >= 0; --k) {
        if (m >= 0 && M[k][m] <= g) m -= (1 << k);
    }
    if (m < 0) m = -1;

    S_out[(b << 9) | t] = S;
    nodes[(b << 9) | t] = Node{g, m};
}

// Kernel 2: one wave = 16 consecutive t of one b; block = 4 waves = 64 t;
// grid 1024 (XCD-chunked swizzle). Node table in LDS (4KB). Descending-m
// sweep: g > M[j] filter IS the record condition -> per-id math identical
// to the chase. Window rows 1x each; below-window rows shared via union
// chain (ngl links + threshold skip). nt-stores (R10 A/B: nt >= plain).
__global__ void __launch_bounds__(256) stack_read(
    const float* __restrict__ v, const float* __restrict__ S_in,
    const Node* __restrict__ nodes, float* __restrict__ out)
{
    __shared__ float2 snode[T_DIM];    // 4 KB: {g, ngl-as-float-bits}

    const int bid = blockIdx.x;                      // 0..1023
    const int swz = ((bid & 7) << 7) | (bid >> 3);   // XCD-chunked (8 XCDs)
    const int base_id = swz << 6;                    // 64 ids per block
    const int b    = base_id >> 9;                   // uniform per block
    const int wv   = threadIdx.x >> 6;               // wave 0..3
    const int lane = threadIdx.x & 63;
    const int e4   = lane << 2;

    {   // stage node table for this b (512 x 8B, two loads per thread)
        const int i = threadIdx.x;                   // 0..255
        const Node n0 = nodes[(b << 9) | i];
        const Node n1 = nodes[(b << 9) | (i + 256)];
        snode[i]       = make_float2(n0.g, __int_as_float(n0.ngl));
        snode[i + 256] = make_float2(n1.g, __int_as_float(n1.ngl));
    }
    __syncthreads();

    const int tw = (base_id & 511) | (wv << 4);      // window start t
    const float* __restrict__ vb = v + (size_t)b * E_DIM + e4;   // + (m<<15)

    float4 acc[W];
    float  M[W], prev[W], S[W];
    #pragma unroll
    for (int j = 0; j < W; ++j) {
        acc[j] = make_float4(0.f, 0.f, 0.f, 0.f);
        M[j] = NEG_INF; prev[j] = 0.f;
        S[j] = S_in[base_id + (wv << 4) + j];
    }

    // Phase A: window rows m = tw+15 .. tw, each loaded exactly once.
    #pragma unroll
    for (int k = W - 1; k >= 0; --k) {
        const int m = tw + k;
        const float2 nd = snode[m];
        const float g = nd.x;
        const float4 vv = *(const float4*)(vb + ((size_t)m << 15));
        #pragma unroll
        for (int j = 0; j < W; ++j) {
            if (j >= k) {                            // m <= t_j (static)
                if (g > M[j]) {                      // record condition
                    const float rc  = S[j] + g;
                    const float cur = fminf(rc, 1.f);
                    const float wt  = cur - prev[j];
                    acc[j].x += wt * vv.x; acc[j].y += wt * vv.y;
                    acc[j].z += wt * vv.z; acc[j].w += wt * vv.w;
                    prev[j] = cur;
                    M[j] = (rc >= 1.f) ? DONE : g;
                }
            }
        }
    }

    // Phase B: shared below-window union chain.
    float thr = M[0];
    #pragma unroll
    for (int j = 1; j < W; ++j) thr = fminf(thr, M[j]);

    if (thr < 1e29f) {
        int p = __float_as_int(snode[tw].y);         // ngl(tw)
        while (p >= 0) {                             // skip to first > thr
            const float2 nd = snode[p];
            if (nd.x > thr) break;
            p = __float_as_int(nd.y);
        }
        while (p >= 0) {
            const float2 nd = snode[p];
            const float g = nd.x;
            const float4 vv = *(const float4*)(vb + ((size_t)p << 15));
            #pragma unroll
            for (int j = 0; j < W; ++j) {
                if (g > M[j]) {
                    const float rc  = S[j] + g;
                    const float cur = fminf(rc, 1.f);
                    const float wt  = cur - prev[j];
                    acc[j].x += wt * vv.x; acc[j].y += wt * vv.y;
                    acc[j].z += wt * vv.z; acc[j].w += wt * vv.w;
                    prev[j] = cur;
                    M[j] = (rc >= 1.f) ? DONE : g;
                }
            }
            thr = M[0];
            #pragma unroll
            for (int j = 1; j < W; ++j) thr = fminf(thr, M[j]);
            if (thr > 1e29f) break;                  // all ids done
            p = __float_as_int(nd.y);
            while (p >= 0) {                         // threshold skip
                const float2 nd2 = snode[p];
                if (nd2.x > thr) break;
                p = __float_as_int(nd2.y);
            }
        }
    }

    #pragma unroll
    for (int j = 0; j < W; ++j) {
        const int t = tw + j;
        const vfloat4 o = {acc[j].x, acc[j].y, acc[j].z, acc[j].w};
        __builtin_nontemporal_store(o,
            (vfloat4*)(out + ((size_t)t * B_DIM + b) * E_DIM + e4));
    }
}

extern "C" void kernel_launch(void* const* d_in, const int* in_sizes, int n_in,
                              void* d_out, int out_size, void* d_ws, size_t ws_size,
                              hipStream_t stream) {
    const float* v = (const float*)d_in[0];
    const float* u = (const float*)d_in[1];
    const float* d = (const float*)d_in[2];
    float* out = (float*)d_out;

    float* S    = (float*)d_ws;                                     // 256 KB
    Node*  node = (Node*)((char*)d_ws + (size_t)B_DIM * T_DIM * 4); // 512 KB

    scan_prep<<<dim3(B_DIM), 512, 0, stream>>>(u, d, S, node);
    stack_read<<<dim3((T_DIM * B_DIM) / 64), 256, 0, stream>>>(v, S, node, out);
}

// Round 12
// 128.004 us; speedup vs baseline: 1.0876x; 1.0876x over previous
//
#include <hip/hip_runtime.h>

#define T_DIM 512
#define B_DIM 128
#define E_DIM 256
#define NEG_INF (-1e30f)
#define W 8          // ids (consecutive t) per wave (R11 showed 16 regresses)
#define DONE 1e30f

typedef float vfloat4 __attribute__((ext_vector_type(4)));  // native vec for nt-store

// Closed-form stack math (exact max-plus identity):
//   rc_t[tau] = S[t] + max_{m in [tau,t]} g[m],  S = incl. prefix sum of (d-u),
//   g[m] = d[m] - S[m].
//   W[t][tau] != 0 only at right-to-left records of g (NGL chain from t),
//   truncated once S[t] + g[m] >= 1.
// FINAL (revert to R9 = best measured, 126.9us total):
//   - windowed descending-m sweep, W=8 ids/wave: window rows load once/id,
//     below-window rows shared via union chain (ngl links + threshold skip)
//   - node table in LDS (4KB), no serial global dependency chains
//   - XCD-chunked swizzle (consecutive blocks -> same XCD L2)
//   - nt-stores (R10 A/B: nt >= plain)
// Falsified axes: HBM bytes (R6), hierarchy bytes at margin (R9 ~45TB/s),
// latency/MLP (R2/R6/R8), LDS row staging (R3), write path (R10), W=16 (R11).

struct Node { float g; int ngl; };   // g value + next-greater-to-left index

// Kernel 1: per-b prep. Shuffle wave-scan for S; sparse-table (range-max
// binary descend) for NGL: fixed 10 LDS probes per thread, no divergent scans.
__global__ void __launch_bounds__(512) scan_prep(
    const float* __restrict__ u, const float* __restrict__ d,
    float* __restrict__ S_out, Node* __restrict__ nodes)
{
    const int b    = blockIdx.x;
    const int t    = threadIdx.x;
    const int lane = t & 63;
    const int w    = t >> 6;          // 8 waves

    __shared__ float wsum[8];
    __shared__ float wpre[8];
    __shared__ float M[10][T_DIM];    // M[k][i] = max g over [max(0,i-2^k+1), i]

    const float dv = d[t * B_DIM + b];
    float x = dv - u[t * B_DIM + b];

    // wave-level inclusive scan (6 shfl steps)
    #pragma unroll
    for (int off = 1; off < 64; off <<= 1) {
        float y = __shfl_up(x, off, 64);
        if (lane >= off) x += y;
    }
    if (lane == 63) wsum[w] = x;
    __syncthreads();
    if (t < 8) {                       // tiny exclusive scan of 8 wave totals
        float s = 0.f;
        for (int i = 0; i < t; ++i) s += wsum[i];
        wpre[t] = s;
    }
    __syncthreads();
    const float S = x + wpre[w];       // inclusive prefix sum of (d-u)
    const float g = dv - S;

    // build sparse table: 9 levels of doubling window max
    M[0][t] = g;
    __syncthreads();
    #pragma unroll
    for (int k = 1; k < 10; ++k) {
        int h = 1 << (k - 1);
        float left = (t >= h) ? M[k - 1][t - h] : NEG_INF;
        float mk = fmaxf(M[k - 1][t], left);
        __syncthreads();               // level k-1 reads done
        M[k][t] = mk;
        __syncthreads();
    }

    // binary descend: largest m < t with g[m] > g (strict); else -1.
    int m = t - 1;
    #pragma unroll
    for (int k = 9; k >= 0; --k) {
        if (m >= 0 && M[k][m] <= g) m -= (1 << k);
    }
    if (m < 0) m = -1;

    S_out[(b << 9) | t] = S;
    nodes[(b << 9) | t] = Node{g, m};
}

// Kernel 2: one wave = 8 consecutive t of one b; block = 4 waves = 32 t;
// grid 2048 (XCD-chunked swizzle). Node table in LDS (4KB). Descending-m
// sweep: g > M[j] filter IS the record condition -> per-id math identical
// to the chase. Window rows 1x each; below-window rows shared via union
// chain (ngl links + threshold skip). nt-stores for the write-once out.
__global__ void __launch_bounds__(256) stack_read(
    const float* __restrict__ v, const float* __restrict__ S_in,
    const Node* __restrict__ nodes, float* __restrict__ out)
{
    __shared__ float2 snode[T_DIM];    // 4 KB: {g, ngl-as-float-bits}

    const int bid = blockIdx.x;                      // 0..2047
    const int swz = ((bid & 7) << 8) | (bid >> 3);   // XCD-chunked (8 XCDs)
    const int base_id = swz << 5;                    // 32 ids per block
    const int b    = base_id >> 9;                   // uniform per block
    const int wv   = threadIdx.x >> 6;               // wave 0..3
    const int lane = threadIdx.x & 63;
    const int e4   = lane << 2;

    {   // stage node table for this b (512 x 8B, two loads per thread)
        const int i = threadIdx.x;                   // 0..255
        const Node n0 = nodes[(b << 9) | i];
        const Node n1 = nodes[(b << 9) | (i + 256)];
        snode[i]       = make_float2(n0.g, __int_as_float(n0.ngl));
        snode[i + 256] = make_float2(n1.g, __int_as_float(n1.ngl));
    }
    __syncthreads();

    const int tw = (base_id & 511) | (wv << 3);      // window start t
    const float* __restrict__ vb = v + (size_t)b * E_DIM + e4;   // + (m<<15)

    float4 acc[W];
    float  M[W], prev[W], S[W];
    #pragma unroll
    for (int j = 0; j < W; ++j) {
        acc[j] = make_float4(0.f, 0.f, 0.f, 0.f);
        M[j] = NEG_INF; prev[j] = 0.f;
        S[j] = S_in[base_id + (wv << 3) + j];
    }

    // Phase A: window rows m = tw+7 .. tw, each loaded exactly once.
    #pragma unroll
    for (int k = W - 1; k >= 0; --k) {
        const int m = tw + k;
        const float2 nd = snode[m];
        const float g = nd.x;
        const float4 vv = *(const float4*)(vb + ((size_t)m << 15));
        #pragma unroll
        for (int j = 0; j < W; ++j) {
            if (j >= k) {                            // m <= t_j
                if (g > M[j]) {                      // record condition
                    const float rc  = S[j] + g;
                    const float cur = fminf(rc, 1.f);
                    const float wt  = cur - prev[j];
                    acc[j].x += wt * vv.x; acc[j].y += wt * vv.y;
                    acc[j].z += wt * vv.z; acc[j].w += wt * vv.w;
                    prev[j] = cur;
                    M[j] = (rc >= 1.f) ? DONE : g;
                }
            }
        }
    }

    // Phase B: shared below-window union chain.
    float thr = M[0];
    #pragma unroll
    for (int j = 1; j < W; ++j) thr = fminf(thr, M[j]);

    if (thr < 1e29f) {
        int p = __float_as_int(snode[tw].y);         // ngl(tw)
        while (p >= 0) {                             // skip to first > thr
            const float2 nd = snode[p];
            if (nd.x > thr) break;
            p = __float_as_int(nd.y);
        }
        while (p >= 0) {
            const float2 nd = snode[p];
            const float g = nd.x;
            const float4 vv = *(const float4*)(vb + ((size_t)p << 15));
            #pragma unroll
            for (int j = 0; j < W; ++j) {
                if (g > M[j]) {
                    const float rc  = S[j] + g;
                    const float cur = fminf(rc, 1.f);
                    const float wt  = cur - prev[j];
                    acc[j].x += wt * vv.x; acc[j].y += wt * vv.y;
                    acc[j].z += wt * vv.z; acc[j].w += wt * vv.w;
                    prev[j] = cur;
                    M[j] = (rc >= 1.f) ? DONE : g;
                }
            }
            thr = M[0];
            #pragma unroll
            for (int j = 1; j < W; ++j) thr = fminf(thr, M[j]);
            if (thr > 1e29f) break;                  // all ids done
            p = __float_as_int(nd.y);
            while (p >= 0) {                         // threshold skip
                const float2 nd2 = snode[p];
                if (nd2.x > thr) break;
                p = __float_as_int(nd2.y);
            }
        }
    }

    #pragma unroll
    for (int j = 0; j < W; ++j) {
        const int t = tw + j;
        const vfloat4 o = {acc[j].x, acc[j].y, acc[j].z, acc[j].w};
        __builtin_nontemporal_store(o,
            (vfloat4*)(out + ((size_t)t * B_DIM + b) * E_DIM + e4));
    }
}

extern "C" void kernel_launch(void* const* d_in, const int* in_sizes, int n_in,
                              void* d_out, int out_size, void* d_ws, size_t ws_size,
                              hipStream_t stream) {
    const float* v = (const float*)d_in[0];
    const float* u = (const float*)d_in[1];
    const float* d = (const float*)d_in[2];
    float* out = (float*)d_out;

    float* S    = (float*)d_ws;                                     // 256 KB
    Node*  node = (Node*)((char*)d_ws + (size_t)B_DIM * T_DIM * 4); // 512 KB

    scan_prep<<<dim3(B_DIM), 512, 0, stream>>>(u, d, S, node);
    stack_read<<<dim3((T_DIM * B_DIM) / 32), 256, 0, stream>>>(v, S, node, out);
}